// Round 1
// baseline (1280.138 us; speedup 1.0000x reference)
//
#include <hip/hip_runtime.h>
#include <stdint.h>

#define B_ 512
#define D_ 1024
#define M_ 32768

// ---------- sortable key helpers (monotonic float <-> u32) ----------
__device__ __forceinline__ unsigned f2k(float f) {
    unsigned b = __float_as_uint(f);
    return (b & 0x80000000u) ? ~b : (b | 0x80000000u);
}
__device__ __forceinline__ float k2f(unsigned k) {
    unsigned b = (k & 0x80000000u) ? (k & 0x7FFFFFFFu) : ~k;
    return __uint_as_float(b);
}

// ---------- encoder GEMM: preact[b][m] = sum_d (x[b][d]-ib[d]) * wenc[m][d] + nb[m]
// fp32 vector ALU. Tile 128(b) x 128(m) x 16(k), 256 threads, 8x8 microtile.
__global__ __launch_bounds__(256) void enc_gemm(
    const float* __restrict__ x, const float* __restrict__ wenc,
    const float* __restrict__ ib, const float* __restrict__ nb,
    float* __restrict__ preact)
{
    __shared__ float As[16][136];  // [k][b-row], pad 136 for store-conflict relief + 16B align
    __shared__ float Bs[16][136];  // [k][m-col]

    const int tid = threadIdx.x;
    const int tx = tid & 15;       // m-group
    const int ty = tid >> 4;       // b-group
    const int i0 = blockIdx.y * 128;  // b base
    const int j0 = blockIdx.x * 128;  // m base

    float acc[8][8];
#pragma unroll
    for (int r = 0; r < 8; ++r)
#pragma unroll
        for (int c = 0; c < 8; ++c) acc[r][c] = 0.0f;

    for (int k0 = 0; k0 < 1024; k0 += 16) {
        // stage A (xc) and B (wenc) tiles: 128x16 each, transposed into [k][row]
#pragma unroll
        for (int l = 0; l < 2; ++l) {
            int v = tid + l * 256;          // 0..511 vec4 slots
            int row = v >> 2;               // 0..127
            int kg = (v & 3) * 4;           // 0,4,8,12
            float4 xa = *(const float4*)(x + (size_t)(i0 + row) * 1024 + k0 + kg);
            float4 ba = *(const float4*)(ib + k0 + kg);
            As[kg + 0][row] = xa.x - ba.x;
            As[kg + 1][row] = xa.y - ba.y;
            As[kg + 2][row] = xa.z - ba.z;
            As[kg + 3][row] = xa.w - ba.w;
            float4 wb = *(const float4*)(wenc + (size_t)(j0 + row) * 1024 + k0 + kg);
            Bs[kg + 0][row] = wb.x;
            Bs[kg + 1][row] = wb.y;
            Bs[kg + 2][row] = wb.z;
            Bs[kg + 3][row] = wb.w;
        }
        __syncthreads();

#pragma unroll
        for (int kk = 0; kk < 16; ++kk) {
            float a[8], bb[8];
            *(float4*)&a[0]  = *(const float4*)&As[kk][ty * 8];
            *(float4*)&a[4]  = *(const float4*)&As[kk][ty * 8 + 4];
            *(float4*)&bb[0] = *(const float4*)&Bs[kk][tx * 4];
            *(float4*)&bb[4] = *(const float4*)&Bs[kk][64 + tx * 4];
#pragma unroll
            for (int r = 0; r < 8; ++r)
#pragma unroll
                for (int c = 0; c < 8; ++c)
                    acc[r][c] += a[r] * bb[c];
        }
        __syncthreads();
    }

    float4 nb0 = *(const float4*)(nb + j0 + tx * 4);
    float4 nb1 = *(const float4*)(nb + j0 + 64 + tx * 4);
#pragma unroll
    for (int r = 0; r < 8; ++r) {
        size_t o = (size_t)(i0 + ty * 8 + r) * M_ + j0;
        float4 o0, o1;
        o0.x = acc[r][0] + nb0.x; o0.y = acc[r][1] + nb0.y;
        o0.z = acc[r][2] + nb0.z; o0.w = acc[r][3] + nb0.w;
        o1.x = acc[r][4] + nb1.x; o1.y = acc[r][5] + nb1.y;
        o1.z = acc[r][6] + nb1.z; o1.w = acc[r][7] + nb1.w;
        *(float4*)(preact + o + tx * 4) = o0;
        *(float4*)(preact + o + 64 + tx * 4) = o1;
    }
}

// ---------- transpose W_dec [1024][32768] -> wdt [32768][1024]
__global__ __launch_bounds__(256) void tr_k(const float* __restrict__ wdec,
                                            float* __restrict__ wdt)
{
    __shared__ float tile[32][33];
    int tx = threadIdx.x, ty = threadIdx.y;
    int x0 = blockIdx.x * 32;  // m
    int y0 = blockIdx.y * 32;  // d
#pragma unroll
    for (int j = 0; j < 32; j += 8)
        tile[ty + j][tx] = wdec[(size_t)(y0 + ty + j) * M_ + x0 + tx];
    __syncthreads();
#pragma unroll
    for (int j = 0; j < 32; j += 8)
        wdt[(size_t)(x0 + ty + j) * D_ + y0 + tx] = tile[tx][ty + j];
}

// ---------- per-row top-R select (radix select on sortable keys) + bitonic sort
// Tie-break matches jax.lax.top_k: equal values -> lower index first.
template <int R, bool MASK>
__global__ __launch_bounds__(256) void select_k(
    const float* __restrict__ preact, const int* __restrict__ steps,
    int* __restrict__ sel_idx, float* __restrict__ sel_val,
    float* __restrict__ out_idx, float* __restrict__ out_val, int outK)
{
    __shared__ unsigned hist[8][257];   // 8 privatized copies, padded
    __shared__ unsigned sh_prefix, sh_remaining;
    __shared__ unsigned gcount, ecount;
    __shared__ unsigned glist[R], gkey[R];
    __shared__ unsigned elist[256];
    __shared__ unsigned long long sortbuf[R];

    const int t = threadIdx.x;
    const int b = blockIdx.x;
    const float* row = preact + (size_t)b * M_;

    unsigned prefix = 0, remaining = (unsigned)R;
    for (int pass = 0; pass < 4; ++pass) {
        int shift = 24 - pass * 8;
        for (int i = t; i < 8 * 257; i += 256) (&hist[0][0])[i] = 0;
        __syncthreads();
        for (int m = t; m < M_; m += 256) {
            float v = row[m];
            if (MASK) v = (steps[m] + 1 > 256) ? v : 0.0f;
            unsigned key = f2k(v);
            bool match = (pass == 0) || ((key >> (shift + 8)) == (prefix >> (shift + 8)));
            if (match) atomicAdd(&hist[t & 7][(key >> shift) & 0xFF], 1u);
        }
        __syncthreads();
        if (t == 0) {
            unsigned cum = 0;
            int tb = 0;
            for (int bin = 255; bin >= 0; --bin) {
                unsigned c = hist[0][bin] + hist[1][bin] + hist[2][bin] + hist[3][bin]
                           + hist[4][bin] + hist[5][bin] + hist[6][bin] + hist[7][bin];
                if (cum + c >= remaining) { tb = bin; break; }
                cum += c;
            }
            sh_prefix = prefix | ((unsigned)tb << shift);
            sh_remaining = remaining - cum;
        }
        __syncthreads();
        prefix = sh_prefix;
        remaining = sh_remaining;
        __syncthreads();
    }

    const unsigned T = prefix;
    if (t == 0) { gcount = 0; ecount = 0; }
    __syncthreads();
    for (int m = t; m < M_; m += 256) {
        float v = row[m];
        if (MASK) v = (steps[m] + 1 > 256) ? v : 0.0f;
        unsigned key = f2k(v);
        if (key > T) {
            unsigned p = atomicAdd(&gcount, 1u);
            if (p < (unsigned)R) { glist[p] = (unsigned)m; gkey[p] = key; }
        } else if (key == T) {
            unsigned p = atomicAdd(&ecount, 1u);
            if (p < 256u) elist[p] = (unsigned)m;
        }
    }
    __syncthreads();

    unsigned gc = gcount;                       // == R - remaining by construction
    if (gc > (unsigned)R) gc = (unsigned)R;
    unsigned ec = ecount > 256u ? 256u : ecount;
    for (unsigned i = t; i < gc; i += 256)
        sortbuf[i] = ((unsigned long long)gkey[i] << 32) | (unsigned)(~glist[i]);
    for (unsigned i = t; i < ec; i += 256) {
        unsigned mi = elist[i];
        unsigned rank = 0;
        for (unsigned j = 0; j < ec; ++j) rank += (elist[j] < mi) ? 1u : 0u;
        if (rank < remaining && gc + rank < (unsigned)R)
            sortbuf[gc + rank] = ((unsigned long long)T << 32) | (unsigned)(~mi);
    }
    __syncthreads();

    // bitonic sort descending by (key, ~idx) => value desc, idx asc on ties
    for (unsigned kk = 2; kk <= (unsigned)R; kk <<= 1) {
        for (unsigned j = kk >> 1; j > 0; j >>= 1) {
            unsigned i = (unsigned)t;
            if (i < (unsigned)R) {
                unsigned ixj = i ^ j;
                if (ixj > i) {
                    unsigned long long a = sortbuf[i], bb = sortbuf[ixj];
                    bool desc = ((i & kk) == 0);
                    if (desc ? (a < bb) : (a > bb)) { sortbuf[i] = bb; sortbuf[ixj] = a; }
                }
            }
            __syncthreads();
        }
    }

    if (t < R) {
        unsigned long long c = sortbuf[t];
        unsigned m = ~((unsigned)c);
        unsigned key = (unsigned)(c >> 32);
        float v = k2f(key);
        float rv = v > 0.0f ? v : 0.0f;
        if (sel_idx) { sel_idx[b * R + t] = (int)m; sel_val[b * R + t] = rv; }
        if (t < outK) {
            out_idx[b * outK + t] = (float)m;
            out_val[b * outK + t] = rv;
        }
    }
}

// ---------- sparse decoder: 4 reconstructions fused, one pass over top-128 rows of wdt
__global__ __launch_bounds__(256) void dec_k(
    const float* __restrict__ wdt, const int* __restrict__ sel_idx,
    const float* __restrict__ sel_val, const float* __restrict__ ib,
    float* __restrict__ o_recon, float* __restrict__ o_multik,
    float* __restrict__ o_mat0, float* __restrict__ o_mat1)
{
    __shared__ int sidx[128];
    __shared__ float sval[128];
    const int b = blockIdx.x, t = threadIdx.x;
    if (t < 128) {
        sidx[t] = sel_idx[b * 128 + t];
        sval[t] = sel_val[b * 128 + t];
    }
    __syncthreads();

    const int d = t * 4;
    float4 bias = *(const float4*)(ib + d);
    float4 rec = bias, mul = bias, m0 = bias, m1 = bias;

    for (int k = 0; k < 128; ++k) {
        int idx = sidx[k];
        float v = sval[k];
        float4 w = *(const float4*)(wdt + (size_t)idx * D_ + d);
        mul.x += v * w.x; mul.y += v * w.y; mul.z += v * w.z; mul.w += v * w.w;
        if (k < 32) {
            rec.x += v * w.x; rec.y += v * w.y; rec.z += v * w.z; rec.w += v * w.w;
            if (idx < 16384) {
                m1.x += v * w.x; m1.y += v * w.y; m1.z += v * w.z; m1.w += v * w.w;
                if (idx < 4096) {
                    m0.x += v * w.x; m0.y += v * w.y; m0.z += v * w.z; m0.w += v * w.w;
                }
            }
        }
    }
    size_t o = (size_t)b * D_ + d;
    *(float4*)(o_recon + o)  = rec;
    *(float4*)(o_multik + o) = mul;
    *(float4*)(o_mat0 + o)   = m0;
    *(float4*)(o_mat1 + o)   = m1;
}

extern "C" void kernel_launch(void* const* d_in, const int* in_sizes, int n_in,
                              void* d_out, int out_size, void* d_ws, size_t ws_size,
                              hipStream_t stream)
{
    const float* x    = (const float*)d_in[0];
    const float* wenc = (const float*)d_in[1];
    const float* wdec = (const float*)d_in[2];
    const float* ib   = (const float*)d_in[3];
    const float* nb   = (const float*)d_in[4];
    const int*   steps = (const int*)d_in[5];
    float* out = (float*)d_out;

    char* ws = (char*)d_ws;
    float* preact = (float*)ws;                                   // 64 MB
    float* wdt    = (float*)(ws + 67108864);                      // 128 MB
    int*   sel_idx = (int*)(ws + 67108864 + 134217728);           // 256 KB
    float* sel_val = (float*)(ws + 67108864 + 134217728 + 262144);// 256 KB

    float* out_recon  = out;
    float* out_multik = out + 524288;
    float* out_mat0   = out + 1048576;
    float* out_mat1   = out + 1572864;
    float* out_tidx   = out + 2097152;
    float* out_tval   = out + 2097152 + 16384;
    float* out_aidx   = out + 2097152 + 32768;
    float* out_aval   = out + 2097152 + 32768 + 32768;

    tr_k<<<dim3(1024, 32), dim3(32, 8), 0, stream>>>(wdec, wdt);
    enc_gemm<<<dim3(256, 4), dim3(256), 0, stream>>>(x, wenc, ib, nb, preact);
    select_k<128, false><<<dim3(512), dim3(256), 0, stream>>>(
        preact, (const int*)nullptr, sel_idx, sel_val, out_tidx, out_tval, 32);
    select_k<64, true><<<dim3(512), dim3(256), 0, stream>>>(
        preact, steps, (int*)nullptr, (float*)nullptr, out_aidx, out_aval, 64);
    dec_k<<<dim3(512), dim3(256), 0, stream>>>(
        wdt, sel_idx, sel_val, ib, out_recon, out_multik, out_mat0, out_mat1);
}

// Round 4
// 814.290 us; speedup vs baseline: 1.5721x; 1.5721x over previous
//
#include <hip/hip_runtime.h>
#include <stdint.h>

#define B_ 512
#define D_ 1024
#define M_ 32768

typedef _Float16 half8 __attribute__((ext_vector_type(8)));
typedef _Float16 half4 __attribute__((ext_vector_type(4)));
typedef float f32x4 __attribute__((ext_vector_type(4)));

// ---------- sortable key helpers (monotonic float <-> u32) ----------
__device__ __forceinline__ unsigned f2k(float f) {
    unsigned b = __float_as_uint(f);
    return (b & 0x80000000u) ? ~b : (b | 0x80000000u);
}
__device__ __forceinline__ float k2f(unsigned k) {
    unsigned b = (k & 0x80000000u) ? (k & 0x7FFFFFFFu) : ~k;
    return __uint_as_float(b);
}

// ---------- async global->LDS (16B per lane, wave-uniform base + lane*16) ----------
__device__ __forceinline__ void gld16(const void* g, void* l) {
    __builtin_amdgcn_global_load_lds(
        (__attribute__((address_space(1))) void*)(uintptr_t)g,
        (__attribute__((address_space(3))) void*)(unsigned)(uintptr_t)l,
        16, 0, 0);
}

// ---------- split x: xc = (x - ib) * 2048 -> fp16 hi + fp16 residual*2048 ----------
__global__ __launch_bounds__(256) void split_x_k(
    const float* __restrict__ x, const float* __restrict__ ib,
    _Float16* __restrict__ xh, _Float16* __restrict__ xr)
{
    int i = blockIdx.x * 256 + threadIdx.x;   // float4 index, 131072 total
    float4 v = ((const float4*)x)[i];
    float4 bb = ((const float4*)ib)[i & 255];
    float a0 = (v.x - bb.x) * 2048.0f;
    float a1 = (v.y - bb.y) * 2048.0f;
    float a2 = (v.z - bb.z) * 2048.0f;
    float a3 = (v.w - bb.w) * 2048.0f;
    _Float16 h0 = (_Float16)a0, h1 = (_Float16)a1, h2 = (_Float16)a2, h3 = (_Float16)a3;
    _Float16 r0 = (_Float16)((a0 - (float)h0) * 2048.0f);
    _Float16 r1 = (_Float16)((a1 - (float)h1) * 2048.0f);
    _Float16 r2 = (_Float16)((a2 - (float)h2) * 2048.0f);
    _Float16 r3 = (_Float16)((a3 - (float)h3) * 2048.0f);
    half4 hv = {h0, h1, h2, h3};
    half4 rv = {r0, r1, r2, r3};
    ((half4*)xh)[i] = hv;
    ((half4*)xr)[i] = rv;
}

// ---------- split W_enc: w*2048 -> fp16 hi + fp16 residual*2048 ----------
__global__ __launch_bounds__(256) void split_w_k(
    const float* __restrict__ w, _Float16* __restrict__ wh, _Float16* __restrict__ wr)
{
    int i = blockIdx.x * 256 + threadIdx.x;   // float4 index, 8388608 total
    float4 v = ((const float4*)w)[i];
    float a0 = v.x * 2048.0f, a1 = v.y * 2048.0f, a2 = v.z * 2048.0f, a3 = v.w * 2048.0f;
    _Float16 h0 = (_Float16)a0, h1 = (_Float16)a1, h2 = (_Float16)a2, h3 = (_Float16)a3;
    _Float16 r0 = (_Float16)((a0 - (float)h0) * 2048.0f);
    _Float16 r1 = (_Float16)((a1 - (float)h1) * 2048.0f);
    _Float16 r2 = (_Float16)((a2 - (float)h2) * 2048.0f);
    _Float16 r3 = (_Float16)((a3 - (float)h3) * 2048.0f);
    half4 hv = {h0, h1, h2, h3};
    half4 rv = {r0, r1, r2, r3};
    ((half4*)wh)[i] = hv;
    ((half4*)wr)[i] = rv;
}

// ---------- encoder GEMM via MFMA fp16, double-word split ----------
__global__ __launch_bounds__(256) void enc_mfma(
    const _Float16* __restrict__ xhf, const _Float16* __restrict__ xrf,
    const _Float16* __restrict__ whf, const _Float16* __restrict__ wrf,
    const float* __restrict__ nb, float* __restrict__ preact)
{
    __shared__ alignas(16) _Float16 lAh[128 * 32];
    __shared__ alignas(16) _Float16 lAr[128 * 32];
    __shared__ alignas(16) _Float16 lBh[128 * 32];
    __shared__ alignas(16) _Float16 lBr[128 * 32];

    const int tid = threadIdx.x;
    const int lane = tid & 63;
    const int wv = tid >> 6;
    const int wvr = wv >> 1;
    const int wvc = wv & 1;
    const int i0 = blockIdx.y * 128;
    const int j0 = blockIdx.x * 128;
    const int ln15 = lane & 15;
    const int kq = (lane >> 4) * 8;

    f32x4 acc1[4][4], acc2[4][4];
#pragma unroll
    for (int r = 0; r < 4; ++r)
#pragma unroll
        for (int c = 0; c < 4; ++c) {
            acc1[r][c] = (f32x4){0.f, 0.f, 0.f, 0.f};
            acc2[r][c] = (f32x4){0.f, 0.f, 0.f, 0.f};
        }

    const int o0 = wv * 1024 + lane * 16;
    const int o1 = o0 + 4096;
    const int r0 = o0 >> 6, c0 = o0 & 63;
    const int r1 = o1 >> 6, c1 = o1 & 63;

    for (int k0 = 0; k0 < 1024; k0 += 32) {
        gld16((const char*)(xhf + (size_t)(i0 + r0) * 1024 + k0) + c0, (char*)lAh + o0);
        gld16((const char*)(xhf + (size_t)(i0 + r1) * 1024 + k0) + c1, (char*)lAh + o1);
        gld16((const char*)(xrf + (size_t)(i0 + r0) * 1024 + k0) + c0, (char*)lAr + o0);
        gld16((const char*)(xrf + (size_t)(i0 + r1) * 1024 + k0) + c1, (char*)lAr + o1);
        gld16((const char*)(whf + (size_t)(j0 + r0) * 1024 + k0) + c0, (char*)lBh + o0);
        gld16((const char*)(whf + (size_t)(j0 + r1) * 1024 + k0) + c1, (char*)lBh + o1);
        gld16((const char*)(wrf + (size_t)(j0 + r0) * 1024 + k0) + c0, (char*)lBr + o0);
        gld16((const char*)(wrf + (size_t)(j0 + r1) * 1024 + k0) + c1, (char*)lBr + o1);
        __syncthreads();

        half8 aH[4], aR[4], bH[4], bR[4];
#pragma unroll
        for (int r = 0; r < 4; ++r) {
            aH[r] = *(const half8*)&lAh[(wvr * 64 + r * 16 + ln15) * 32 + kq];
            aR[r] = *(const half8*)&lAr[(wvr * 64 + r * 16 + ln15) * 32 + kq];
            bH[r] = *(const half8*)&lBh[(wvc * 64 + r * 16 + ln15) * 32 + kq];
            bR[r] = *(const half8*)&lBr[(wvc * 64 + r * 16 + ln15) * 32 + kq];
        }
#pragma unroll
        for (int r = 0; r < 4; ++r)
#pragma unroll
            for (int c = 0; c < 4; ++c) {
                acc1[r][c] = __builtin_amdgcn_mfma_f32_16x16x32_f16(aH[r], bH[c], acc1[r][c], 0, 0, 0);
                acc2[r][c] = __builtin_amdgcn_mfma_f32_16x16x32_f16(aH[r], bR[c], acc2[r][c], 0, 0, 0);
                acc2[r][c] = __builtin_amdgcn_mfma_f32_16x16x32_f16(aR[r], bH[c], acc2[r][c], 0, 0, 0);
            }
        __syncthreads();
    }

    const float s1 = 0x1p-22f, s2 = 0x1p-33f;
#pragma unroll
    for (int c = 0; c < 4; ++c) {
        int n = j0 + wvc * 64 + c * 16 + ln15;
        float nbv = nb[n];
#pragma unroll
        for (int r = 0; r < 4; ++r) {
            int mb = i0 + wvr * 64 + r * 16 + (lane >> 4) * 4;
#pragma unroll
            for (int e = 0; e < 4; ++e)
                preact[(size_t)(mb + e) * M_ + n] = acc1[r][c][e] * s1 + acc2[r][c][e] * s2 + nbv;
        }
    }
}

// ---------- transpose W_dec [1024][32768] -> wdt [32768][1024] ----------
__global__ __launch_bounds__(256) void tr_k(const float* __restrict__ wdec,
                                            float* __restrict__ wdt)
{
    __shared__ float tile[32][33];
    int tx = threadIdx.x, ty = threadIdx.y;
    int x0 = blockIdx.x * 32;
    int y0 = blockIdx.y * 32;
#pragma unroll
    for (int j = 0; j < 32; j += 8)
        tile[ty + j][tx] = wdec[(size_t)(y0 + ty + j) * M_ + x0 + tx];
    __syncthreads();
#pragma unroll
    for (int j = 0; j < 32; j += 8)
        wdt[(size_t)(x0 + ty + j) * D_ + y0 + tx] = tile[tx][ty + j];
}

// ---------- fused dual top-k select (MFMA-order): top-128 unmasked + masked cands ----------
__global__ __launch_bounds__(256) void select_both(
    const float* __restrict__ preact, const int* __restrict__ steps,
    int* __restrict__ sel_idx, float* __restrict__ sel_val,
    int* __restrict__ auxcand)
{
    __shared__ unsigned histU[4096];
    __shared__ unsigned histM[4096];
    __shared__ unsigned coarse[256];
    __shared__ unsigned long long candU[512];
    __shared__ unsigned long long candM[512];
    __shared__ unsigned cntU, cntM, thrU, thrM;

    const int t = threadIdx.x;
    const int b = blockIdx.x;
    const float* row = preact + (size_t)b * M_;

    for (int i = t; i < 4096; i += 256) { histU[i] = 0; histM[i] = 0; }
    candU[t] = 0ULL; candU[t + 256] = 0ULL;
    candM[t] = 0ULL; candM[t + 256] = 0ULL;
    if (t == 0) { cntU = 0; cntM = 0; }
    __syncthreads();

    for (int m = t; m < M_; m += 256) {
        unsigned key = f2k(row[m]);
        atomicAdd(&histU[key >> 20], 1u);
        bool dead = (steps[m] + 1) > 256;
        atomicAdd(&histM[dead ? (key >> 20) : 2048u], 1u);
    }
    __syncthreads();

    { unsigned s = 0;
#pragma unroll
      for (int j = 0; j < 16; ++j) s += histU[t * 16 + j];
      coarse[t] = s; }
    __syncthreads();
    if (t == 0) {
        unsigned cum = 0; int cb = 0;
        for (int c = 255; c >= 0; --c) { if (cum + coarse[c] >= 128u) { cb = c; break; } cum += coarse[c]; }
        int tb = cb * 16;
        for (int f = cb * 16 + 15; f >= cb * 16; --f) { if (cum + histU[f] >= 128u) { tb = f; break; } cum += histU[f]; }
        thrU = (unsigned)tb;
    }
    __syncthreads();
    { unsigned s = 0;
#pragma unroll
      for (int j = 0; j < 16; ++j) s += histM[t * 16 + j];
      coarse[t] = s; }
    __syncthreads();
    if (t == 0) {
        unsigned cum = 0; int cb = 0;
        for (int c = 255; c >= 0; --c) { if (cum + coarse[c] >= 64u) { cb = c; break; } cum += coarse[c]; }
        int tb = cb * 16;
        for (int f = cb * 16 + 15; f >= cb * 16; --f) { if (cum + histM[f] >= 64u) { tb = f; break; } cum += histM[f]; }
        thrM = (unsigned)(tb > 0 ? tb - 1 : 0);   // one extra bin: margin for top-96 resolve superset
    }
    __syncthreads();

    const unsigned TU = thrU, TM = thrM;

    for (int m = t; m < M_; m += 256) {
        unsigned key = f2k(row[m]);
        if ((key >> 20) >= TU) {
            unsigned p = atomicAdd(&cntU, 1u);
            if (p < 512u) candU[p] = ((unsigned long long)key << 32) | (unsigned)(~m);
        }
        bool dead = (steps[m] + 1) > 256;
        if (dead && (key >> 20) >= TM) {
            unsigned p = atomicAdd(&cntM, 1u);
            if (p < 512u) candM[p] = ((unsigned long long)key << 32) | (unsigned)(~m);
        }
    }
    __syncthreads();

    for (unsigned kk = 2; kk <= 512; kk <<= 1) {
        for (unsigned j = kk >> 1; j > 0; j >>= 1) {
#pragma unroll
            for (int h = 0; h < 2; ++h) {
                unsigned i = (unsigned)t + (unsigned)h * 256u;
                unsigned ixj = i ^ j;
                if (ixj > i) {
                    bool desc = ((i & kk) == 0);
                    unsigned long long a = candU[i], c = candU[ixj];
                    if (desc ? (a < c) : (a > c)) { candU[i] = c; candU[ixj] = a; }
                    a = candM[i]; c = candM[ixj];
                    if (desc ? (a < c) : (a > c)) { candM[i] = c; candM[ixj] = a; }
                }
            }
            __syncthreads();
        }
    }

    if (t < 128) {
        unsigned long long c = candU[t];
        unsigned m = ~(unsigned)c;
        float v = k2f((unsigned)(c >> 32));
        sel_idx[b * 128 + t] = (int)m;
        sel_val[b * 128 + t] = v > 0.f ? v : 0.f;
    }
    if (t < 96) {
        unsigned long long c = candM[t];
        auxcand[b * 96 + t] = c ? (int)(~(unsigned)c) : -1;
    }
}

// ---------- exact resolve: recompute candidate dots in fp32 sequential-k FMA order ----------
// (replicates round-1 summation order, which matched the np reference exactly)
__global__ __launch_bounds__(256) void resolve_k(
    const float* __restrict__ x, const float* __restrict__ ib,
    const float* __restrict__ wenc, const float* __restrict__ nb,
    const int* __restrict__ sel_idx, const int* __restrict__ auxcand,
    int* __restrict__ rec32_idx, float* __restrict__ rec32_val,
    float* __restrict__ out_tidx, float* __restrict__ out_tval,
    float* __restrict__ out_aidx, float* __restrict__ out_aval)
{
    __shared__ float xcs[1024];
    __shared__ unsigned long long kU[64];
    __shared__ unsigned long long kM[128];

    const int b = blockIdx.x, t = threadIdx.x;
    for (int d = t; d < 1024; d += 256) xcs[d] = x[(size_t)b * 1024 + d] - ib[d];
    if (t < 64) kU[t] = 0ULL;
    if (t < 128) kM[t] = 0ULL;
    __syncthreads();

    int m = -1;
    if (t < 48) m = sel_idx[b * 128 + t];
    else if (t >= 64 && t < 160) m = auxcand[b * 96 + (t - 64)];
    if (m >= 0) {
        const float* w = wenc + (size_t)m * 1024;
        float acc = 0.0f;
        for (int d = 0; d < 1024; d += 4) {
            float4 wv = *(const float4*)(w + d);
            acc = fmaf(xcs[d + 0], wv.x, acc);
            acc = fmaf(xcs[d + 1], wv.y, acc);
            acc = fmaf(xcs[d + 2], wv.z, acc);
            acc = fmaf(xcs[d + 3], wv.w, acc);
        }
        float v = acc + nb[m];
        unsigned long long key = ((unsigned long long)f2k(v) << 32) | (unsigned)(~m);
        if (t < 48) kU[t] = key; else kM[t - 64] = key;
    }
    __syncthreads();

    for (unsigned kk = 2; kk <= 128; kk <<= 1) {
        for (unsigned j = kk >> 1; j > 0; j >>= 1) {
            unsigned i = (unsigned)t, ixj = i ^ j;
            if (kk <= 64 && i < 64 && ixj > i) {
                bool desc = ((i & kk) == 0);
                unsigned long long a = kU[i], c = kU[ixj];
                if (desc ? (a < c) : (a > c)) { kU[i] = c; kU[ixj] = a; }
            }
            if (i < 128 && ixj > i) {
                bool desc = ((i & kk) == 0);
                unsigned long long a = kM[i], c = kM[ixj];
                if (desc ? (a < c) : (a > c)) { kM[i] = c; kM[ixj] = a; }
            }
            __syncthreads();
        }
    }

    if (t < 32) {
        unsigned long long c = kU[t];
        unsigned mm = ~(unsigned)c;
        float v = k2f((unsigned)(c >> 32));
        float rv = v > 0.f ? v : 0.f;
        rec32_idx[b * 32 + t] = (int)mm;
        rec32_val[b * 32 + t] = rv;
        out_tidx[b * 32 + t] = (float)mm;
        out_tval[b * 32 + t] = rv;
    }
    if (t < 64) {
        unsigned long long c = kM[t];
        unsigned mm = ~(unsigned)c;
        float v = k2f((unsigned)(c >> 32));
        out_aidx[b * 64 + t] = (float)mm;
        out_aval[b * 64 + t] = v > 0.f ? v : 0.f;
    }
}

// ---------- sparse decoder: multik from MFMA top-128, recon/mat from exact top-32 ----------
__global__ __launch_bounds__(256) void dec_k(
    const float* __restrict__ wdt, const int* __restrict__ sel_idx,
    const float* __restrict__ sel_val, const int* __restrict__ rec32_idx,
    const float* __restrict__ rec32_val, const float* __restrict__ ib,
    float* __restrict__ o_recon, float* __restrict__ o_multik,
    float* __restrict__ o_mat0, float* __restrict__ o_mat1)
{
    __shared__ int sidx[128];
    __shared__ float sval[128];
    __shared__ int ridx[32];
    __shared__ float rval[32];
    const int b = blockIdx.x, t = threadIdx.x;
    if (t < 128) { sidx[t] = sel_idx[b * 128 + t]; sval[t] = sel_val[b * 128 + t]; }
    if (t < 32)  { ridx[t] = rec32_idx[b * 32 + t]; rval[t] = rec32_val[b * 32 + t]; }
    __syncthreads();

    const int d = t * 4;
    float4 bias = *(const float4*)(ib + d);
    float4 mul = bias, rec = bias, m0 = bias, m1 = bias;

    for (int k = 0; k < 128; ++k) {
        float v = sval[k];
        float4 w = *(const float4*)(wdt + (size_t)sidx[k] * D_ + d);
        mul.x += v * w.x; mul.y += v * w.y; mul.z += v * w.z; mul.w += v * w.w;
    }
    for (int k = 0; k < 32; ++k) {
        int idx = ridx[k];
        float v = rval[k];
        float4 w = *(const float4*)(wdt + (size_t)idx * D_ + d);
        rec.x += v * w.x; rec.y += v * w.y; rec.z += v * w.z; rec.w += v * w.w;
        if (idx < 16384) {
            m1.x += v * w.x; m1.y += v * w.y; m1.z += v * w.z; m1.w += v * w.w;
            if (idx < 4096) {
                m0.x += v * w.x; m0.y += v * w.y; m0.z += v * w.z; m0.w += v * w.w;
            }
        }
    }
    size_t o = (size_t)b * D_ + d;
    *(float4*)(o_recon + o)  = rec;
    *(float4*)(o_multik + o) = mul;
    *(float4*)(o_mat0 + o)   = m0;
    *(float4*)(o_mat1 + o)   = m1;
}

extern "C" void kernel_launch(void* const* d_in, const int* in_sizes, int n_in,
                              void* d_out, int out_size, void* d_ws, size_t ws_size,
                              hipStream_t stream)
{
    const float* x     = (const float*)d_in[0];
    const float* wenc  = (const float*)d_in[1];
    const float* wdec  = (const float*)d_in[2];
    const float* ib    = (const float*)d_in[3];
    const float* nb    = (const float*)d_in[4];
    const int*   steps = (const int*)d_in[5];
    float* out = (float*)d_out;

    char* ws = (char*)d_ws;
    float*     preact  = (float*)ws;                              // [0, 64MB)
    _Float16*  whf     = (_Float16*)(ws + 67108864);              // [64MB, 128MB)
    _Float16*  wrf     = (_Float16*)(ws + 134217728);             // [128MB, 192MB)
    float*     wdt     = (float*)(ws + 67108864);                 // aliases whf/wrf (dead after GEMM)
    _Float16*  xhf     = (_Float16*)(ws + 201326592);             // [192MB, +1MB)
    _Float16*  xrf     = (_Float16*)(ws + 202375168);             // [193MB, +1MB)
    int*       auxcand = (int*)(ws + 201326592);                  // aliases xhf (dead after GEMM), 192KB
    int*       rec32_i = (int*)(ws + 201326592 + 262144);         // 64KB
    float*     rec32_v = (float*)(ws + 201326592 + 327680);       // 64KB
    int*       sel_idx = (int*)(ws + 203423744);                  // [194MB, +256KB)
    float*     sel_val = (float*)(ws + 203685888);                // +256KB

    float* out_recon  = out;
    float* out_multik = out + 524288;
    float* out_mat0   = out + 1048576;
    float* out_mat1   = out + 1572864;
    float* out_tidx   = out + 2097152;
    float* out_tval   = out + 2097152 + 16384;
    float* out_aidx   = out + 2097152 + 32768;
    float* out_aval   = out + 2097152 + 32768 + 32768;

    split_x_k<<<dim3(512), dim3(256), 0, stream>>>(x, ib, xhf, xrf);
    split_w_k<<<dim3(32768), dim3(256), 0, stream>>>(wenc, whf, wrf);
    enc_mfma<<<dim3(256, 4), dim3(256), 0, stream>>>(xhf, xrf, whf, wrf, nb, preact);
    tr_k<<<dim3(1024, 32), dim3(32, 8), 0, stream>>>(wdec, wdt);   // after enc (wdt aliases W splits)
    select_both<<<dim3(512), dim3(256), 0, stream>>>(preact, steps, sel_idx, sel_val, auxcand);
    resolve_k<<<dim3(512), dim3(256), 0, stream>>>(
        x, ib, wenc, nb, sel_idx, auxcand, rec32_i, rec32_v,
        out_tidx, out_tval, out_aidx, out_aval);
    dec_k<<<dim3(512), dim3(256), 0, stream>>>(
        wdt, sel_idx, sel_val, rec32_i, rec32_v, ib,
        out_recon, out_multik, out_mat0, out_mat1);
}